// Round 3
// baseline (399.226 us; speedup 1.0000x reference)
//
#include <hip/hip_runtime.h>

#define NN 8192
#define HD 512
#define NL 3
#define CAP 128
#define LN_EPS 1e-5f

typedef _Float16 f16;
typedef _Float16 f16x8 __attribute__((ext_vector_type(8)));
typedef _Float16 f16x4 __attribute__((ext_vector_type(4)));
typedef float f32x4 __attribute__((ext_vector_type(4)));

__device__ __forceinline__ unsigned short f16_bits(f16 h) {
  union { f16 h; unsigned short u; } x; x.h = h; return x.u;
}
__device__ __forceinline__ f16 bits_f16(unsigned short u) {
  union { unsigned short u; f16 h; } x; x.u = u; return x.h;
}

// ---------------------------------------------------------------------------
// k_prep: one HBM pass over dense A (f32, symmetric, zero diag, entries >= 0).
// Row staged in REGISTERS (8 float4/thread) -- no big LDS buffer, so occupancy
// is not LDS-capped and the kernel runs at the HBM read floor.
// Emits ELL rows: packed u32 = (f16(w) << 16) | col, plus self-loop w=1
// (diag of A is always 0 by construction), padded with w=0 to a multiple of 8.
// deg = rowsum + 1 -> dinv = deg^-1/2.
__global__ __launch_bounds__(256) void k_prep(const float* __restrict__ A,
                                              unsigned* __restrict__ ell,
                                              int* __restrict__ nnz8,
                                              float* __restrict__ dinv) {
  __shared__ int wtot[4];
  __shared__ float wsum[4];
  const int r = blockIdx.x;
  const int t = threadIdx.x;
  const int lane = t & 63;
  const int wv = t >> 6;
  const float4* ar = (const float4*)(A + (size_t)r * NN);
  unsigned* er = ell + (size_t)r * CAP;

  float4 v[8];
  int c = 0;
  float s = 0.f;
  #pragma unroll
  for (int i = 0; i < 8; i++) {
    v[i] = ar[t + i * 256];
    c += (v[i].x > 0.f) + (v[i].y > 0.f) + (v[i].z > 0.f) + (v[i].w > 0.f);
    s += v[i].x + v[i].y + v[i].z + v[i].w;   // entries are >= 0
  }
  // wave inclusive scan of counts
  int inc = c;
  #pragma unroll
  for (int d = 1; d < 64; d <<= 1) {
    int vv = __shfl_up(inc, d);
    if (lane >= d) inc += vv;
  }
  float ss = s;
  #pragma unroll
  for (int m = 1; m < 64; m <<= 1) ss += __shfl_xor(ss, m);
  if (lane == 63) wtot[wv] = inc;
  if (lane == 0) wsum[wv] = ss;
  __syncthreads();
  int base = inc - c;                       // exclusive within wave
  for (int w = 0; w < wv; w++) base += wtot[w];

  int o = base;
  #pragma unroll
  for (int i = 0; i < 8; i++) {
    float vals[4] = {v[i].x, v[i].y, v[i].z, v[i].w};
    #pragma unroll
    for (int q = 0; q < 4; q++) {
      float val = vals[q];
      if (val > 0.f) {
        if (o < CAP) er[o] = ((unsigned)f16_bits((f16)val) << 16) | (unsigned)((t + i * 256) * 4 + q);
        o++;
      }
    }
  }
  if (t == 255) {
    int ne = wtot[0] + wtot[1] + wtot[2] + wtot[3];
    if (ne < CAP) er[ne] = (0x3C00u << 16) | (unsigned)r;   // self-loop w=1.0
    int ne1 = ne + 1; if (ne1 > CAP) ne1 = CAP;
    int n8 = (ne1 + 7) & ~7;
    for (int k = ne1; k < n8; k++) er[k] = (unsigned)r;     // w = +0.0 pad
    nnz8[r] = n8;
    float deg = wsum[0] + wsum[1] + wsum[2] + wsum[3] + 1.f;
    dinv[r] = rsqrtf(deg);
  }
}

// ---------------------------------------------------------------------------
// xs[r][c] = x0[r][c] * dinv[r]  (f32 -> f16 row-major), 4 elems/thread.
__global__ __launch_bounds__(256) void k_scalex(const float* __restrict__ x0,
                                                const float* __restrict__ dinv,
                                                f16* __restrict__ xs) {
  const size_t idx = (size_t)blockIdx.x * 256 + threadIdx.x;   // over NN*HD/4
  const float4 v = ((const float4*)x0)[idx];
  const float s = dinv[(int)(idx >> 7)];
  f16x4 o = {(f16)(v.x * s), (f16)(v.y * s), (f16)(v.z * s), (f16)(v.w * s)};
  ((f16x4*)xs)[idx] = o;
}

// ---------------------------------------------------------------------------
// SpMM: y[r] = dinv[r] * sum_e w_e * xs[col_e].  One wave per row; each lane
// owns 8 of the 512 columns.  Row index forced wave-uniform (scalar edge
// loads); 8 gathers in flight per iteration.
__global__ __launch_bounds__(256) void k_spmm(const unsigned* __restrict__ ell,
                                              const int* __restrict__ nnz8,
                                              const float* __restrict__ dinv,
                                              const f16* __restrict__ xs,
                                              f16* __restrict__ y) {
  const int r = __builtin_amdgcn_readfirstlane(blockIdx.x * 4 + (threadIdx.x >> 6));
  const int lane = threadIdx.x & 63;
  const unsigned* er = ell + (size_t)r * CAP;
  const int ne = nnz8[r];
  float acc[8] = {0.f, 0.f, 0.f, 0.f, 0.f, 0.f, 0.f, 0.f};
  for (int e = 0; e < ne; e += 8) {
    unsigned wv[8];
    f16x8 xv[8];
    float fw[8];
    #pragma unroll
    for (int q = 0; q < 8; q++) wv[q] = er[e + q];
    #pragma unroll
    for (int q = 0; q < 8; q++)
      xv[q] = *(const f16x8*)(xs + (size_t)(wv[q] & 0xFFFFu) * HD + lane * 8);
    #pragma unroll
    for (int q = 0; q < 8; q++) fw[q] = (float)bits_f16((unsigned short)(wv[q] >> 16));
    #pragma unroll
    for (int j = 0; j < 8; j++) {
      float a = acc[j];
      #pragma unroll
      for (int q = 0; q < 8; q++) a = fmaf(fw[q], (float)xv[q][j], a);
      acc[j] = a;
    }
  }
  const float s = dinv[r];
  f16x8 o;
  #pragma unroll
  for (int j = 0; j < 8; j++) o[j] = (f16)(acc[j] * s);
  *(f16x8*)(y + (size_t)r * HD + lane * 8) = o;
}

// ---------------------------------------------------------------------------
// Fused GEMM + bias + LayerNorm + ReLU + optional dinv scale, f16 out.
// C[16 x 512] per block; 512 threads = 8 waves, wave w owns cols w*64..+64
// (4 n-frags of 16x16, K=512).  LN reduce: 16-lane shfl_xor + LDS across waves.
__global__ __launch_bounds__(512) void k_gemm_ln(const f16* __restrict__ y,
                                                 const f16* __restrict__ WT,
                                                 const float* __restrict__ bias,
                                                 const float* __restrict__ g,
                                                 const float* __restrict__ bb,
                                                 const float* __restrict__ dscale,
                                                 f16* __restrict__ outp) {
  __shared__ float red[16][8][2];
  const int t = threadIdx.x;
  const int lane = t & 63;
  const int w = t >> 6;
  const int m0 = blockIdx.x * 16;
  const int rl = lane & 15, kg = (lane >> 4) * 8;
  const int nc0 = w * 64;
  const f16* aP = y + (size_t)(m0 + rl) * HD + kg;
  const f16* bP = WT + (size_t)(nc0 + rl) * HD + kg;

  f32x4 acc[4];
  #pragma unroll
  for (int j = 0; j < 4; j++) { f32x4 z = {0.f, 0.f, 0.f, 0.f}; acc[j] = z; }

  #pragma unroll 2
  for (int ks = 0; ks < HD; ks += 32) {
    const f16x8 af = *(const f16x8*)(aP + ks);
    #pragma unroll
    for (int j = 0; j < 4; j++) {
      const f16x8 bf = *(const f16x8*)(bP + (size_t)j * 16 * HD + ks);
      acc[j] = __builtin_amdgcn_mfma_f32_16x16x32_f16(af, bf, acc[j], 0, 0, 0);
    }
  }

  const int cg = lane >> 4, cl = lane & 15;
  float av[4][4];
  #pragma unroll
  for (int j = 0; j < 4; j++) {
    const float bv = bias[nc0 + j * 16 + cl];
    #pragma unroll
    for (int r = 0; r < 4; r++) av[j][r] = acc[j][r] + bv;
  }
  #pragma unroll
  for (int r = 0; r < 4; r++) {
    float s = av[0][r] + av[1][r] + av[2][r] + av[3][r];
    float sq = av[0][r] * av[0][r] + av[1][r] * av[1][r] +
               av[2][r] * av[2][r] + av[3][r] * av[3][r];
    #pragma unroll
    for (int m = 1; m < 16; m <<= 1) { s += __shfl_xor(s, m); sq += __shfl_xor(sq, m); }
    if (cl == 0) { red[cg * 4 + r][w][0] = s; red[cg * 4 + r][w][1] = sq; }
  }
  __syncthreads();
  #pragma unroll
  for (int r = 0; r < 4; r++) {
    const int rb = cg * 4 + r;
    float s = 0.f, sq = 0.f;
    #pragma unroll
    for (int q = 0; q < 8; q++) { s += red[rb][q][0]; sq += red[rb][q][1]; }
    const float mu = s * (1.f / HD);
    const float rs = rsqrtf(sq * (1.f / HD) - mu * mu + LN_EPS);
    const int row = m0 + rb;
    const float dsc = dscale ? dscale[row] : 1.f;
    #pragma unroll
    for (int j = 0; j < 4; j++) {
      const int col = nc0 + j * 16 + cl;
      const float val = fmaxf((av[j][r] - mu) * rs * g[col] + bb[col], 0.f) * dsc;
      outp[(size_t)row * HD + col] = (f16)val;
    }
  }
}

// ---------------------------------------------------------------------------
// Direct-from-L2 MFMA GEMM (final linear): C[M,512] = A[M,512] @ BT^T + bias.
__global__ __launch_bounds__(256) void k_gemm_direct(const f16* __restrict__ A,
                                                     const f16* __restrict__ BT,
                                                     float* __restrict__ C,
                                                     const float* __restrict__ bias) {
  const int t = threadIdx.x;
  const int lane = t & 63;
  const int wave = t >> 6;
  const int wm = wave >> 1, wn = wave & 1;
  const int m0 = blockIdx.x * 128, n0 = blockIdx.y * 128;
  const int rl = lane & 15, kg = (lane >> 4) * 8;

  const f16* aP[4];
  const f16* bP[4];
  #pragma unroll
  for (int i = 0; i < 4; i++)
    aP[i] = A + (size_t)(m0 + wm * 64 + i * 16 + rl) * HD + kg;
  #pragma unroll
  for (int j = 0; j < 4; j++)
    bP[j] = BT + (size_t)(n0 + wn * 64 + j * 16 + rl) * HD + kg;

  f32x4 acc[4][4];
  #pragma unroll
  for (int i = 0; i < 4; i++)
    #pragma unroll
    for (int j = 0; j < 4; j++) {
      f32x4 z = {0.f, 0.f, 0.f, 0.f};
      acc[i][j] = z;
    }

  #pragma unroll 4
  for (int ks = 0; ks < HD; ks += 32) {
    f16x8 af[4], bf[4];
    #pragma unroll
    for (int i = 0; i < 4; i++) af[i] = *(const f16x8*)(aP[i] + ks);
    #pragma unroll
    for (int j = 0; j < 4; j++) bf[j] = *(const f16x8*)(bP[j] + ks);
    #pragma unroll
    for (int i = 0; i < 4; i++)
      #pragma unroll
      for (int j = 0; j < 4; j++)
        acc[i][j] = __builtin_amdgcn_mfma_f32_16x16x32_f16(af[i], bf[j], acc[i][j], 0, 0, 0);
  }

  const int cg = lane >> 4, cl = lane & 15;
  #pragma unroll
  for (int i = 0; i < 4; i++) {
    #pragma unroll
    for (int j = 0; j < 4; j++) {
      const int col = n0 + wn * 64 + j * 16 + cl;
      const float bv = bias ? bias[col] : 0.f;
      #pragma unroll
      for (int rr = 0; rr < 4; rr++) {
        const int row = m0 + wm * 64 + i * 16 + cg * 4 + rr;
        C[(size_t)row * HD + col] = acc[i][j][rr] + bv;
      }
    }
  }
}

// ---------------------------------------------------------------------------
// WlT[n][m] = (Wc @ Wm)[m][n], f16.  k-outer: Wm row in registers (coalesced),
// Wc via uniform scalar loads.  grid (64, NL), 256 threads, 8 m-rows/block.
__global__ __launch_bounds__(256) void k_wcomb(const float* __restrict__ convw,
                                               const float* __restrict__ mlpw,
                                               f16* __restrict__ WlT) {
  const int l = blockIdx.y;
  const int m0 = blockIdx.x * 8;
  const float* Wc = convw + (size_t)l * HD * HD;
  const float* Wm = mlpw + (size_t)l * HD * HD;
  f16* o = WlT + (size_t)l * HD * HD;
  const int n = threadIdx.x;
  float a0[8] = {0, 0, 0, 0, 0, 0, 0, 0};
  float a1[8] = {0, 0, 0, 0, 0, 0, 0, 0};
  for (int k = 0; k < HD; k++) {
    const float w0 = Wm[(size_t)k * HD + n];
    const float w1 = Wm[(size_t)k * HD + n + 256];
    #pragma unroll
    for (int mi = 0; mi < 8; mi++) {
      const float wc = Wc[(size_t)(m0 + mi) * HD + k];
      a0[mi] = fmaf(wc, w0, a0[mi]);
      a1[mi] = fmaf(wc, w1, a1[mi]);
    }
  }
  #pragma unroll
  for (int mi = 0; mi < 8; mi++) {
    o[(size_t)n * HD + m0 + mi] = (f16)a0[mi];
    o[(size_t)(n + 256) * HD + m0 + mi] = (f16)a1[mi];
  }
}

// bl[l][n] = conv_b[l] @ Wm[l] + mlp_b[l][n].  grid NL, block HD.
__global__ void k_bcomb(const float* __restrict__ convb, const float* __restrict__ mlpw,
                        const float* __restrict__ mlpb, float* __restrict__ bl) {
  const int l = blockIdx.x;
  const int n = threadIdx.x;
  const float* Wm = mlpw + (size_t)l * HD * HD;
  float acc = mlpb[l * HD + n];
  for (int k = 0; k < HD; k++) acc = fmaf(convb[l * HD + k], Wm[(size_t)k * HD + n], acc);
  bl[l * HD + n] = acc;
}

// lwT[n][k] = lin_w[k][n], f32 -> f16.  grid HD, block 256.
__global__ __launch_bounds__(256) void k_twl(const float* __restrict__ lw,
                                             f16* __restrict__ lwT) {
  const int k = blockIdx.x;
  for (int n = threadIdx.x; n < HD; n += 256)
    lwT[(size_t)n * HD + k] = (f16)lw[(size_t)k * HD + n];
}

// ---------------------------------------------------------------------------
extern "C" void kernel_launch(void* const* d_in, const int* in_sizes, int n_in,
                              void* d_out, int out_size, void* d_ws, size_t ws_size,
                              hipStream_t stream) {
  const float* node_feat = (const float*)d_in[0];
  const float* adj       = (const float*)d_in[1];
  const float* conv_w    = (const float*)d_in[2];
  const float* conv_b    = (const float*)d_in[3];
  const float* mlp_w     = (const float*)d_in[4];
  const float* mlp_b     = (const float*)d_in[5];
  const float* ln_g      = (const float*)d_in[6];
  const float* ln_b      = (const float*)d_in[7];
  const float* lin_w     = (const float*)d_in[8];
  const float* lin_b     = (const float*)d_in[9];
  float* out = (float*)d_out;

  // workspace carve (~38 MB)
  char* p = (char*)d_ws;
  unsigned* ell = (unsigned*)p; p += (size_t)NN * CAP * 4;   // 4 MB
  int* nnz8  = (int*)p;   p += (size_t)NN * 4;
  float* dinv = (float*)p; p += (size_t)NN * 4;
  f16* xsA   = (f16*)p;   p += (size_t)NN * HD * 2;          // 8 MB
  f16* xsB   = (f16*)p;   p += (size_t)NN * HD * 2;          // 8 MB
  f16* ybuf  = (f16*)p;   p += (size_t)NN * HD * 2;          // 8 MB
  f16* WlT   = (f16*)p;   p += (size_t)NL * HD * HD * 2;
  f16* lwT   = (f16*)p;   p += (size_t)HD * HD * 2;
  float* bl  = (float*)p; p += (size_t)NL * HD * 4;

  k_prep<<<NN, 256, 0, stream>>>(adj, ell, nnz8, dinv);
  k_scalex<<<NN * HD / 4 / 256, 256, 0, stream>>>(node_feat, dinv, xsA);
  k_wcomb<<<dim3(64, NL), 256, 0, stream>>>(conv_w, mlp_w, WlT);
  k_bcomb<<<NL, HD, 0, stream>>>(conv_b, mlp_w, mlp_b, bl);
  k_twl<<<HD, 256, 0, stream>>>(lin_w, lwT);

  f16* xcur = xsA;
  for (int l = 0; l < NL; l++) {
    k_spmm<<<NN / 4, 256, 0, stream>>>(ell, nnz8, dinv, xcur, ybuf);
    f16* nxt = (xcur == xsA) ? xsB : xsA;
    k_gemm_ln<<<NN / 16, 512, 0, stream>>>(ybuf, WlT + (size_t)l * HD * HD,
                                           bl + l * HD, ln_g + l * HD, ln_b + l * HD,
                                           (l < 2) ? dinv : nullptr, nxt);
    xcur = nxt;
  }
  k_gemm_direct<<<dim3(64, 4), 256, 0, stream>>>(xcur, lwT, out, lin_b);
}

// Round 4
// 367.750 us; speedup vs baseline: 1.0856x; 1.0856x over previous
//
#include <hip/hip_runtime.h>

#define NN 8192
#define HD 512
#define NL 3
#define CAP 128
#define LN_EPS 1e-5f

typedef _Float16 f16;
typedef _Float16 f16x8 __attribute__((ext_vector_type(8)));
typedef _Float16 f16x4 __attribute__((ext_vector_type(4)));
typedef _Float16 f16x2 __attribute__((ext_vector_type(2)));
typedef float f32x4 __attribute__((ext_vector_type(4)));

__device__ __forceinline__ unsigned short f16_bits(f16 h) {
  union { f16 h; unsigned short u; } x; x.h = h; return x.u;
}
__device__ __forceinline__ f16 bits_f16(unsigned short u) {
  union { unsigned short u; f16 h; } x; x.u = u; return x.h;
}

// ---------------------------------------------------------------------------
// k_prep (round-2 structure): one HBM pass over dense A. Row staged in LDS,
// wave-scan for ELL compaction.  Emits packed u32 = (f16(w)<<16) | col, plus
// self-loop w=1 (diag of A is 0 by construction), padded with w=0 to a
// multiple of 8.  deg = rowsum + 1 -> dinv = deg^-1/2.
__global__ __launch_bounds__(256) void k_prep(const float* __restrict__ A,
                                              unsigned* __restrict__ ell,
                                              int* __restrict__ nnz8,
                                              float* __restrict__ dinv) {
  __shared__ float rowbuf[NN];     // 32 KB staged row
  __shared__ int wtot[4];
  __shared__ float wsum[4];
  const int r = blockIdx.x;
  const int t = threadIdx.x;
  const int lane = t & 63;
  const int wv = t >> 6;
  const float4* ar = (const float4*)(A + (size_t)r * NN);
  unsigned* er = ell + (size_t)r * CAP;

  int c = 0;
  float s = 0.f;
  for (int i = t; i < NN / 4; i += 256) {
    float4 v = ar[i];
    ((float4*)rowbuf)[i] = v;
    c += (v.x > 0.f) + (v.y > 0.f) + (v.z > 0.f) + (v.w > 0.f);
    s += v.x + v.y + v.z + v.w;   // entries are >= 0
  }
  // wave inclusive scan of counts
  int inc = c;
  #pragma unroll
  for (int d = 1; d < 64; d <<= 1) {
    int v = __shfl_up(inc, d);
    if (lane >= d) inc += v;
  }
  float ss = s;
  #pragma unroll
  for (int m = 1; m < 64; m <<= 1) ss += __shfl_xor(ss, m);
  if (lane == 63) wtot[wv] = inc;
  if (lane == 0) wsum[wv] = ss;
  __syncthreads();
  int base = inc - c;                       // exclusive within wave
  for (int w = 0; w < wv; w++) base += wtot[w];

  int o = base;
  for (int i = t; i < NN / 4; i += 256) {
    float4 v = ((float4*)rowbuf)[i];
    float vals[4] = {v.x, v.y, v.z, v.w};
    #pragma unroll
    for (int q = 0; q < 4; q++) {
      float val = vals[q];
      if (val > 0.f) {
        if (o < CAP) er[o] = ((unsigned)f16_bits((f16)val) << 16) | (unsigned)(i * 4 + q);
        o++;
      }
    }
  }
  if (t == 255) {
    int ne = wtot[0] + wtot[1] + wtot[2] + wtot[3];
    if (ne < CAP) er[ne] = (0x3C00u << 16) | (unsigned)r;   // self-loop w=1.0
    int ne1 = ne + 1; if (ne1 > CAP) ne1 = CAP;
    int n8 = (ne1 + 7) & ~7;
    for (int k = ne1; k < n8; k++) er[k] = (unsigned)r;     // w = +0.0 pad
    nnz8[r] = n8;
    float deg = wsum[0] + wsum[1] + wsum[2] + wsum[3] + 1.f;
    dinv[r] = rsqrtf(deg);
  }
}

// ---------------------------------------------------------------------------
// xs[r][c] = x0[r][c] * dinv[r]  (f32 -> f16 row-major), 4 elems/thread.
__global__ __launch_bounds__(256) void k_scalex(const float* __restrict__ x0,
                                                const float* __restrict__ dinv,
                                                f16* __restrict__ xs) {
  const size_t idx = (size_t)blockIdx.x * 256 + threadIdx.x;   // over NN*HD/4
  const float4 v = ((const float4*)x0)[idx];
  const float s = dinv[(int)(idx >> 7)];
  f16x4 o = {(f16)(v.x * s), (f16)(v.y * s), (f16)(v.z * s), (f16)(v.w * s)};
  ((f16x4*)xs)[idx] = o;
}

// ---------------------------------------------------------------------------
// Column-chunked SpMM: y[r] = dinv[r] * sum_e w_e * xs[col_e].
// bid = chunk*2048 + rowblock; 4 waves/block each own one row, all waves of a
// block share the 128-col chunk.  Per edge each lane gathers f16x2 (4 B) from
// the chunk -- working set per chunk = 8192*256 B = 2 MB, L2-resident per XCD;
// the 2048 blocks of a chunk are exactly one co-resident dispatch phase.
__global__ __launch_bounds__(256) void k_spmm(const unsigned* __restrict__ ell,
                                              const int* __restrict__ nnz8,
                                              const float* __restrict__ dinv,
                                              const f16* __restrict__ xs,
                                              f16* __restrict__ y) {
  const int bid = blockIdx.x;              // 0..8191
  const int chunk = bid >> 11;             // 0..3
  const int rb = bid & 2047;
  const int r = __builtin_amdgcn_readfirstlane(rb * 4 + (threadIdx.x >> 6));
  const int lane = threadIdx.x & 63;
  const int c0 = chunk * 128 + lane * 2;
  const unsigned* er = ell + (size_t)r * CAP;
  const int ne = nnz8[r];
  float a0 = 0.f, a1 = 0.f;
  for (int e = 0; e < ne; e += 8) {
    unsigned wv[8];
    #pragma unroll
    for (int q = 0; q < 8; q++) wv[q] = er[e + q];
    f16x2 xv[8];
    #pragma unroll
    for (int q = 0; q < 8; q++)
      xv[q] = *(const f16x2*)(xs + (size_t)(wv[q] & 0xFFFFu) * HD + c0);
    #pragma unroll
    for (int q = 0; q < 8; q++) {
      const float fw = (float)bits_f16((unsigned short)(wv[q] >> 16));
      a0 = fmaf(fw, (float)xv[q][0], a0);
      a1 = fmaf(fw, (float)xv[q][1], a1);
    }
  }
  const float s = dinv[r];
  f16x2 o = {(f16)(a0 * s), (f16)(a1 * s)};
  *(f16x2*)(y + (size_t)r * HD + c0) = o;
}

// ---------------------------------------------------------------------------
// Direct-from-L2 MFMA GEMM: C[M,512] = A[M,512] @ BT^T + bias.
// 128x128 block, 4 waves 2x2 of 64x64, K = 512 in 16 steps, unroll 4.
// Writes f32 (Cf) or f16 (Ch).
__global__ __launch_bounds__(256) void k_gemm_direct(const f16* __restrict__ A,
                                                     const f16* __restrict__ BT,
                                                     float* __restrict__ Cf,
                                                     f16* __restrict__ Ch,
                                                     const float* __restrict__ bias) {
  const int t = threadIdx.x;
  const int lane = t & 63;
  const int wave = t >> 6;
  const int wm = wave >> 1, wn = wave & 1;
  const int m0 = blockIdx.x * 128, n0 = blockIdx.y * 128;
  const int rl = lane & 15, kg = (lane >> 4) * 8;

  const f16* aP[4];
  const f16* bP[4];
  #pragma unroll
  for (int i = 0; i < 4; i++)
    aP[i] = A + (size_t)(m0 + wm * 64 + i * 16 + rl) * HD + kg;
  #pragma unroll
  for (int j = 0; j < 4; j++)
    bP[j] = BT + (size_t)(n0 + wn * 64 + j * 16 + rl) * HD + kg;

  f32x4 acc[4][4];
  #pragma unroll
  for (int i = 0; i < 4; i++)
    #pragma unroll
    for (int j = 0; j < 4; j++) {
      f32x4 z = {0.f, 0.f, 0.f, 0.f};
      acc[i][j] = z;
    }

  #pragma unroll 4
  for (int ks = 0; ks < HD; ks += 32) {
    f16x8 af[4], bf[4];
    #pragma unroll
    for (int i = 0; i < 4; i++) af[i] = *(const f16x8*)(aP[i] + ks);
    #pragma unroll
    for (int j = 0; j < 4; j++) bf[j] = *(const f16x8*)(bP[j] + ks);
    #pragma unroll
    for (int i = 0; i < 4; i++)
      #pragma unroll
      for (int j = 0; j < 4; j++)
        acc[i][j] = __builtin_amdgcn_mfma_f32_16x16x32_f16(af[i], bf[j], acc[i][j], 0, 0, 0);
  }

  const int cg = lane >> 4, cl = lane & 15;
  #pragma unroll
  for (int i = 0; i < 4; i++) {
    #pragma unroll
    for (int j = 0; j < 4; j++) {
      const int col = n0 + wn * 64 + j * 16 + cl;
      const float bv = bias ? bias[col] : 0.f;
      #pragma unroll
      for (int rr = 0; rr < 4; rr++) {
        const int row = m0 + wm * 64 + i * 16 + cg * 4 + rr;
        const float v = acc[i][j][rr] + bv;
        if (Cf) Cf[(size_t)row * HD + col] = v;
        else Ch[(size_t)row * HD + col] = (f16)v;
      }
    }
  }
}

// ---------------------------------------------------------------------------
// WlT[n][m] = (Wc @ Wm)[m][n], f16.  k-outer: Wm row coalesced, Wc scalar.
__global__ __launch_bounds__(256) void k_wcomb(const float* __restrict__ convw,
                                               const float* __restrict__ mlpw,
                                               f16* __restrict__ WlT) {
  const int l = blockIdx.y;
  const int m0 = blockIdx.x * 8;
  const float* Wc = convw + (size_t)l * HD * HD;
  const float* Wm = mlpw + (size_t)l * HD * HD;
  f16* o = WlT + (size_t)l * HD * HD;
  const int n = threadIdx.x;
  float a0[8] = {0, 0, 0, 0, 0, 0, 0, 0};
  float a1[8] = {0, 0, 0, 0, 0, 0, 0, 0};
  for (int k = 0; k < HD; k++) {
    const float w0 = Wm[(size_t)k * HD + n];
    const float w1 = Wm[(size_t)k * HD + n + 256];
    #pragma unroll
    for (int mi = 0; mi < 8; mi++) {
      const float wc = Wc[(size_t)(m0 + mi) * HD + k];
      a0[mi] = fmaf(wc, w0, a0[mi]);
      a1[mi] = fmaf(wc, w1, a1[mi]);
    }
  }
  #pragma unroll
  for (int mi = 0; mi < 8; mi++) {
    o[(size_t)n * HD + m0 + mi] = (f16)a0[mi];
    o[(size_t)(n + 256) * HD + m0 + mi] = (f16)a1[mi];
  }
}

// bl[l][n] = conv_b[l] @ Wm[l] + mlp_b[l][n].
__global__ void k_bcomb(const float* __restrict__ convb, const float* __restrict__ mlpw,
                        const float* __restrict__ mlpb, float* __restrict__ bl) {
  const int l = blockIdx.x;
  const int n = threadIdx.x;
  const float* Wm = mlpw + (size_t)l * HD * HD;
  float acc = mlpb[l * HD + n];
  for (int k = 0; k < HD; k++) acc = fmaf(convb[l * HD + k], Wm[(size_t)k * HD + n], acc);
  bl[l * HD + n] = acc;
}

// lwT[n][k] = lin_w[k][n], f32 -> f16.
__global__ __launch_bounds__(256) void k_twl(const float* __restrict__ lw,
                                             f16* __restrict__ lwT) {
  const int k = blockIdx.x;
  for (int n = threadIdx.x; n < HD; n += 256)
    lwT[(size_t)n * HD + k] = (f16)lw[(size_t)k * HD + n];
}

// ---------------------------------------------------------------------------
// LayerNorm + ReLU over f16 h rows; writes f16 row-major, optional dinv
// pre-scale.  One wave per row, f16x8 vector loads (16 B/lane).
__global__ __launch_bounds__(256) void k_ln(const f16* __restrict__ Hb,
                                            const float* __restrict__ g,
                                            const float* __restrict__ b,
                                            const float* __restrict__ dscale,
                                            f16* __restrict__ outp) {
  const int row = blockIdx.x * 4 + (threadIdx.x >> 6);
  const int lane = threadIdx.x & 63;
  const f16x8 hv = *(const f16x8*)(Hb + (size_t)row * HD + lane * 8);
  float vals[8];
  #pragma unroll
  for (int q = 0; q < 8; q++) vals[q] = (float)hv[q];
  float s = 0.f, sq = 0.f;
  #pragma unroll
  for (int q = 0; q < 8; q++) { s += vals[q]; sq += vals[q] * vals[q]; }
  #pragma unroll
  for (int m = 1; m < 64; m <<= 1) { s += __shfl_xor(s, m); sq += __shfl_xor(sq, m); }
  const float mu = s * (1.f / HD);
  const float rs = rsqrtf(sq * (1.f / HD) - mu * mu + LN_EPS);
  const float dsc = dscale ? dscale[row] : 1.f;
  f16x8 o;
  #pragma unroll
  for (int q = 0; q < 8; q++) {
    const int c = lane * 8 + q;
    o[q] = (f16)(fmaxf((vals[q] - mu) * rs * g[c] + b[c], 0.f) * dsc);
  }
  *(f16x8*)(outp + (size_t)row * HD + lane * 8) = o;
}

// ---------------------------------------------------------------------------
extern "C" void kernel_launch(void* const* d_in, const int* in_sizes, int n_in,
                              void* d_out, int out_size, void* d_ws, size_t ws_size,
                              hipStream_t stream) {
  const float* node_feat = (const float*)d_in[0];
  const float* adj       = (const float*)d_in[1];
  const float* conv_w    = (const float*)d_in[2];
  const float* conv_b    = (const float*)d_in[3];
  const float* mlp_w     = (const float*)d_in[4];
  const float* mlp_b     = (const float*)d_in[5];
  const float* ln_g      = (const float*)d_in[6];
  const float* ln_b      = (const float*)d_in[7];
  const float* lin_w     = (const float*)d_in[8];
  const float* lin_b     = (const float*)d_in[9];
  float* out = (float*)d_out;

  // workspace carve (~37 MB)
  char* p = (char*)d_ws;
  unsigned* ell = (unsigned*)p; p += (size_t)NN * CAP * 4;   // 4 MB
  int* nnz8  = (int*)p;   p += (size_t)NN * 4;
  float* dinv = (float*)p; p += (size_t)NN * 4;
  f16* xsA   = (f16*)p;   p += (size_t)NN * HD * 2;          // 8 MB
  f16* xsB   = (f16*)p;   p += (size_t)NN * HD * 2;          // 8 MB
  f16* ybuf  = (f16*)p;   p += (size_t)NN * HD * 2;          // 8 MB
  f16* hbuf  = (f16*)p;   p += (size_t)NN * HD * 2;          // 8 MB
  f16* WlT   = (f16*)p;   p += (size_t)NL * HD * HD * 2;
  f16* lwT   = (f16*)p;   p += (size_t)HD * HD * 2;
  float* bl  = (float*)p; p += (size_t)NL * HD * 4;

  k_prep<<<NN, 256, 0, stream>>>(adj, ell, nnz8, dinv);
  k_scalex<<<NN * HD / 4 / 256, 256, 0, stream>>>(node_feat, dinv, xsA);
  k_wcomb<<<dim3(64, NL), 256, 0, stream>>>(conv_w, mlp_w, WlT);
  k_bcomb<<<NL, HD, 0, stream>>>(conv_b, mlp_w, mlp_b, bl);
  k_twl<<<HD, 256, 0, stream>>>(lin_w, lwT);

  f16* xcur = xsA;
  for (int l = 0; l < NL; l++) {
    k_spmm<<<NN * 4 / 4, 256, 0, stream>>>(ell, nnz8, dinv, xcur, ybuf);
    k_gemm_direct<<<dim3(64, 4), 256, 0, stream>>>(ybuf, WlT + (size_t)l * HD * HD,
                                                   nullptr, hbuf, bl + l * HD);
    f16* nxt = (xcur == xsA) ? xsB : xsA;
    k_ln<<<NN / 4, 256, 0, stream>>>(hbuf, ln_g + l * HD, ln_b + l * HD,
                                     (l < 2) ? dinv : nullptr, nxt);
    xcur = nxt;
  }
  k_gemm_direct<<<dim3(64, 4), 256, 0, stream>>>(xcur, lwT, out, nullptr, lin_b);
}